// Round 7
// baseline (15.765 us; speedup 1.0000x reference)
//
#include <hip/hip_runtime.h>
#include <math.h>

#define PRE_LEN 64
#define BATCH   1024
#define NNB     256

// Math (validated R4-R6, absmax 0.0):
//   rotation preserves norm: x^2+y^2 = r2
//   x^6+y^6 = r2*(r2^2 - 3*(x*y)^2),  x*y = dx*dy*cos(2a) - (dx^2-dy^2)*(ca*sa)
//   energy_i/r = 60 * rsq(den^2 * r2);  final norm is sign-invariant.
//
// R7 structure: 256 thr/block, one batch/block. Each thread handles TWO
// timesteps per ds_read (R6 LDS-pipe model: 1 b128 per 17 VALU put ~5.1us
// on the per-CU LDS unit, more than the 3.6us VALU floor — so halve it):
//   lane l: p = l&31 -> t0=2p, t1=2p+1 ; chunk c = (l>>5) + 2*wave ; 32 iters.
// Half-waves read addrs 512B apart = same banks -> 2-way conflict = free.
__global__ __launch_bounds__(256, 4) void field_loss_stage1(
    const float* __restrict__ output,   // [PRE_LEN][BATCH][2]
    const float* __restrict__ target,   // [PRE_LEN][BATCH][2]
    const float* __restrict__ nbr,      // [BATCH][NNB][5]
    float* __restrict__ ws)             // [BATCH] partials
{
    __shared__ float4 s_nb[NNB];        // {nx, ny, cos(2a), ca*sa}
    __shared__ float4 s_red[4][32];     // {ex0,ey0,ex1,ey1} per (wave, p)

    const int b   = blockIdx.x;
    const int tid = threadIdx.x;
    const int l   = tid & 63;
    const int q   = tid >> 6;           // wave 0..3
    const int p   = l & 31;             // t-pair index
    const int t0  = 2 * p;

    // Issue the strided output/target loads FIRST so their HBM/L2 latency
    // hides under nbr staging + sincos.
    const size_t o0 = (size_t)t0 * (BATCH * 2) + (size_t)b * 2;
    const size_t o1 = o0 + (BATCH * 2);
    const float2 pxy0 = *reinterpret_cast<const float2*>(&output[o0]);
    const float2 pxy1 = *reinterpret_cast<const float2*>(&output[o1]);
    const float2 txy0 = *reinterpret_cast<const float2*>(&target[o0]);
    const float2 txy1 = *reinterpret_cast<const float2*>(&target[o1]);

    {
        const float* pn = nbr + ((size_t)b * NNB + tid) * 5;
        const float nx  = pn[0];
        const float ny  = pn[1];
        const float ang = pn[4];
        const float rev = ang * 0.31830988618f;         // (2a)/(2*pi)
        const float c2  = __builtin_amdgcn_cosf(rev);   // cos(2a)
        const float s2  = __builtin_amdgcn_sinf(rev);   // sin(2a)
        s_nb[tid] = make_float4(nx, ny, c2, 0.5f * s2); // 0.5*sin(2a) = ca*sa
    }
    __syncthreads();

    const float px0 = pxy0.x, py0 = pxy0.y;
    const float px1 = pxy1.x, py1 = pxy1.y;

    float ex0 = 0.0f, ey0 = 0.0f, ex1 = 0.0f, ey1 = 0.0f;
    const int n0 = ((l >> 5) + 2 * q) * 32;   // chunk base, 8 chunks of 32
#pragma unroll 4
    for (int i = 0; i < 32; ++i) {
        const float4 nb = s_nb[n0 + i];
        // timestep t0
        {
            const float dx  = px0 - nb.x;
            const float dy  = py0 - nb.y;
            const float dx2 = dx * dx;
            const float pp  = dx * dy;
            const float r2  = __builtin_fmaf(dy, dy, dx2);
            const float qq  = __builtin_fmaf(-dy, dy, dx2);
            const float xy  = __builtin_fmaf(pp, nb.z, -(qq * nb.w));
            const float inr = __builtin_fmaf(xy * xy, -3.0f, r2 * r2);
            const float den = __builtin_fmaf(r2, inr, 6.0f);
            const float s   = 60.0f * __builtin_amdgcn_rsqf(den * den * r2);
            ex0 = __builtin_fmaf(s, dx, ex0);
            ey0 = __builtin_fmaf(s, dy, ey0);
        }
        // timestep t1
        {
            const float dx  = px1 - nb.x;
            const float dy  = py1 - nb.y;
            const float dx2 = dx * dx;
            const float pp  = dx * dy;
            const float r2  = __builtin_fmaf(dy, dy, dx2);
            const float qq  = __builtin_fmaf(-dy, dy, dx2);
            const float xy  = __builtin_fmaf(pp, nb.z, -(qq * nb.w));
            const float inr = __builtin_fmaf(xy * xy, -3.0f, r2 * r2);
            const float den = __builtin_fmaf(r2, inr, 6.0f);
            const float s   = 60.0f * __builtin_amdgcn_rsqf(den * den * r2);
            ex1 = __builtin_fmaf(s, dx, ex1);
            ey1 = __builtin_fmaf(s, dy, ey1);
        }
    }

    // combine the two half-waves (lane l and l^32 share p, differ in chunk)
    ex0 += __shfl_xor(ex0, 32, 64);
    ey0 += __shfl_xor(ey0, 32, 64);
    ex1 += __shfl_xor(ex1, 32, 64);
    ey1 += __shfl_xor(ey1, 32, 64);

    if (l < 32)
        s_red[q][p] = make_float4(ex0, ey0, ex1, ey1);
    __syncthreads();

    if (q == 0) {
        // all 64 lanes run; lanes l and l+32 duplicate p = l&31
        float tex0 = 0.0f, tey0 = 0.0f, tex1 = 0.0f, tey1 = 0.0f;
        #pragma unroll
        for (int k = 0; k < 4; ++k) {
            const float4 r = s_red[k][p];
            tex0 += r.x; tey0 += r.y; tex1 += r.z; tey1 += r.w;
        }
        const float en0 = __builtin_amdgcn_sqrtf(
            __builtin_fmaf(tex0, tex0, tey0 * tey0));
        const float en1 = __builtin_amdgcn_sqrtf(
            __builtin_fmaf(tex1, tex1, tey1 * tey1));

        const float d0x = px0 - txy0.x, d0y = py0 - txy0.y;
        const float d1x = px1 - txy1.x, d1y = py1 - txy1.y;

        float val = (en0 + en1) * (1.0f / (PRE_LEN * BATCH))
                  + (d0x * d0x + d0y * d0y + d1x * d1x + d1y * d1y)
                    * (1.0f / (PRE_LEN * BATCH * 2));

        // lanes 0-31 hold the 32 distinct vals (32-63 are duplicates):
        // reduce with offsets 16..1 so lane 0 sums exactly lanes 0..31.
        #pragma unroll
        for (int off = 16; off > 0; off >>= 1)
            val += __shfl_down(val, off, 64);

        if (l == 0)
            ws[b] = val;            // plain store, one per block
    }
}

// Stage 2: ONE wave, no LDS, no barrier. 1024 floats = 256 float4.
__global__ __launch_bounds__(64) void reduce_kernel(
    const float4* __restrict__ ws4,  // [256]
    float* __restrict__ out)         // [1]
{
    const int l = threadIdx.x;
    const float4 a = ws4[l];
    const float4 b = ws4[l + 64];
    const float4 c = ws4[l + 128];
    const float4 d = ws4[l + 192];
    float v = ((a.x + a.y) + (a.z + a.w)) + ((b.x + b.y) + (b.z + b.w))
            + ((c.x + c.y) + (c.z + c.w)) + ((d.x + d.y) + (d.z + d.w));

    #pragma unroll
    for (int off = 32; off > 0; off >>= 1)
        v += __shfl_down(v, off, 64);

    if (l == 0)
        out[0] = v;
}

extern "C" void kernel_launch(void* const* d_in, const int* in_sizes, int n_in,
                              void* d_out, int out_size, void* d_ws, size_t ws_size,
                              hipStream_t stream) {
    const float* output = (const float*)d_in[0];
    const float* target = (const float*)d_in[1];
    const float* nbr    = (const float*)d_in[2];
    float* out = (float*)d_out;
    float* ws  = (float*)d_ws;      // >= 1024 floats, 16B-aligned

    field_loss_stage1<<<dim3(BATCH), dim3(256), 0, stream>>>(output, target, nbr, ws);
    reduce_kernel<<<dim3(1), dim3(64), 0, stream>>>((const float4*)ws, out);
}

// Round 8
// 14.262 us; speedup vs baseline: 1.1054x; 1.1054x over previous
//
#include <hip/hip_runtime.h>
#include <math.h>

#define PRE_LEN 64
#define BATCH   1024
#define NNB     256

typedef float v2f __attribute__((ext_vector_type(2)));

// Math (validated R4-R7, absmax 0.0):
//   rotation preserves norm: x^2+y^2 = r2
//   x^6+y^6 = r2*(r2^2 - 3*(x*y)^2),  x*y = dx*dy*cos(2a) - (dx^2-dy^2)*(ca*sa)
//   energy_i/r = 60 * rsq(den^2 * r2);  final norm is sign-invariant.
//
// R8: same structure as R7 (256 thr, lane l: t-pair p=l&31 -> t0=2p,2p+1;
// chunk (l>>5)+2q; 32 iters) but the two timestep chains are PACKED into
// float2 ext-vectors -> v_pk_fma_f32/v_pk_mul_f32 (VOP3P), halving VALU
// instruction issue (R5 HW datum: ~6.4us VALU busy; R7 null showed LDS is
// not the limiter -> test whether VALU issue is the critical path).
__global__ __launch_bounds__(256, 4) void field_loss_stage1(
    const float* __restrict__ output,   // [PRE_LEN][BATCH][2]
    const float* __restrict__ target,   // [PRE_LEN][BATCH][2]
    const float* __restrict__ nbr,      // [BATCH][NNB][5]
    float* __restrict__ ws)             // [BATCH] partials
{
    __shared__ float4 s_nb[NNB];        // {nx, ny, cos(2a), ca*sa}
    __shared__ float4 s_red[4][32];     // {ex0,ey0,ex1,ey1} per (wave, p)

    const int b   = blockIdx.x;
    const int tid = threadIdx.x;
    const int l   = tid & 63;
    const int q   = tid >> 6;           // wave 0..3
    const int p   = l & 31;             // t-pair index
    const int t0  = 2 * p;

    // Issue strided output loads first (latency hides under staging+sincos).
    const size_t o0 = (size_t)t0 * (BATCH * 2) + (size_t)b * 2;
    const size_t o1 = o0 + (BATCH * 2);
    const float2 a0 = *reinterpret_cast<const float2*>(&output[o0]);
    const float2 a1 = *reinterpret_cast<const float2*>(&output[o1]);
    // target only consumed by wave 0's tail
    float2 tg0 = make_float2(0.f, 0.f), tg1 = make_float2(0.f, 0.f);
    if (q == 0) {
        tg0 = *reinterpret_cast<const float2*>(&target[o0]);
        tg1 = *reinterpret_cast<const float2*>(&target[o1]);
    }

    {
        const float* pn = nbr + ((size_t)b * NNB + tid) * 5;
        const float nx  = pn[0];
        const float ny  = pn[1];
        const float ang = pn[4];
        const float rev = ang * 0.31830988618f;         // (2a)/(2*pi)
        const float c2  = __builtin_amdgcn_cosf(rev);   // cos(2a)
        const float s2  = __builtin_amdgcn_sinf(rev);   // sin(2a)
        s_nb[tid] = make_float4(nx, ny, c2, 0.5f * s2); // 0.5*sin(2a) = ca*sa
    }
    __syncthreads();

    const v2f px = { a0.x, a1.x };
    const v2f py = { a0.y, a1.y };

    v2f ex = 0.0f, ey = 0.0f;
    const int n0 = ((l >> 5) + 2 * q) * 32;   // chunk base, 8 chunks of 32
#pragma unroll 8
    for (int i = 0; i < 32; ++i) {
        const float4 nb = s_nb[n0 + i];       // uniform addr -> broadcast
        const v2f dx  = px - nb.x;                              // pk_add
        const v2f dy  = py - nb.y;
        const v2f dx2 = dx * dx;                                // pk_mul
        const v2f pp  = dx * dy;
        const v2f r2  = __builtin_elementwise_fma(dy, dy, dx2); // pk_fma
        const v2f qq  = __builtin_elementwise_fma(dy, -dy, dx2);// dx^2-dy^2
        const v2f xy  = __builtin_elementwise_fma(pp, (v2f)nb.z,
                                                  -(qq * nb.w));
        const v2f inr = __builtin_elementwise_fma(xy * -3.0f, xy, r2 * r2);
        const v2f den = __builtin_elementwise_fma(r2, inr, (v2f)6.0f);
        const v2f m2  = den * den * r2;
        const v2f s   = { 60.0f * __builtin_amdgcn_rsqf(m2.x),
                          60.0f * __builtin_amdgcn_rsqf(m2.y) };
        ex = __builtin_elementwise_fma(s, dx, ex);
        ey = __builtin_elementwise_fma(s, dy, ey);
    }

    // combine half-waves (lane l and l^32 share p, differ in chunk)
    float ex0 = ex.x + __shfl_xor(ex.x, 32, 64);
    float ey0 = ey.x + __shfl_xor(ey.x, 32, 64);
    float ex1 = ex.y + __shfl_xor(ex.y, 32, 64);
    float ey1 = ey.y + __shfl_xor(ey.y, 32, 64);

    if (l < 32)
        s_red[q][p] = make_float4(ex0, ey0, ex1, ey1);
    __syncthreads();

    if (q == 0) {
        float tex0 = 0.0f, tey0 = 0.0f, tex1 = 0.0f, tey1 = 0.0f;
        #pragma unroll
        for (int k = 0; k < 4; ++k) {
            const float4 r = s_red[k][p];
            tex0 += r.x; tey0 += r.y; tex1 += r.z; tey1 += r.w;
        }
        const float en0 = __builtin_amdgcn_sqrtf(
            __builtin_fmaf(tex0, tex0, tey0 * tey0));
        const float en1 = __builtin_amdgcn_sqrtf(
            __builtin_fmaf(tex1, tex1, tey1 * tey1));

        const float d0x = a0.x - tg0.x, d0y = a0.y - tg0.y;
        const float d1x = a1.x - tg1.x, d1y = a1.y - tg1.y;

        float val = (en0 + en1) * (1.0f / (PRE_LEN * BATCH))
                  + (d0x * d0x + d0y * d0y + d1x * d1x + d1y * d1y)
                    * (1.0f / (PRE_LEN * BATCH * 2));

        // lanes 0-31 hold the 32 distinct vals (32-63 duplicate)
        #pragma unroll
        for (int off = 16; off > 0; off >>= 1)
            val += __shfl_down(val, off, 64);

        if (l == 0)
            ws[b] = val;            // plain store, one per block
    }
}

// Stage 2: ONE wave, no LDS, no barrier. 1024 floats = 256 float4.
__global__ __launch_bounds__(64) void reduce_kernel(
    const float4* __restrict__ ws4,  // [256]
    float* __restrict__ out)         // [1]
{
    const int l = threadIdx.x;
    const float4 a = ws4[l];
    const float4 b = ws4[l + 64];
    const float4 c = ws4[l + 128];
    const float4 d = ws4[l + 192];
    float v = ((a.x + a.y) + (a.z + a.w)) + ((b.x + b.y) + (b.z + b.w))
            + ((c.x + c.y) + (c.z + c.w)) + ((d.x + d.y) + (d.z + d.w));

    #pragma unroll
    for (int off = 32; off > 0; off >>= 1)
        v += __shfl_down(v, off, 64);

    if (l == 0)
        out[0] = v;
}

extern "C" void kernel_launch(void* const* d_in, const int* in_sizes, int n_in,
                              void* d_out, int out_size, void* d_ws, size_t ws_size,
                              hipStream_t stream) {
    const float* output = (const float*)d_in[0];
    const float* target = (const float*)d_in[1];
    const float* nbr    = (const float*)d_in[2];
    float* out = (float*)d_out;
    float* ws  = (float*)d_ws;      // >= 1024 floats, 16B-aligned

    field_loss_stage1<<<dim3(BATCH), dim3(256), 0, stream>>>(output, target, nbr, ws);
    reduce_kernel<<<dim3(1), dim3(64), 0, stream>>>((const float4*)ws, out);
}